// Round 7
// baseline (454.693 us; speedup 1.0000x reference)
//
#include <hip/hip_runtime.h>
#include <hip/hip_bf16.h>

// CANLayer round 7: dual-wave gather, lookback scan, fused att+scatter.
//   K0  memset  : zero cnt_l|cnt_u|scan-flags
//   K1  prep    : cvt_x (bf16) + cvt_w (bf16,T) + hist/rank   [grid-stride]
//   K2  gemm    : LDS-staged-B MFMA; xm_low/up + skipb all bf16
//   K3  scan    : single-kernel decoupled-lookback exclusive scan -> ro
//   K4  attscat : blocks [0,12500) att scalars; [12500,15625) CSR scatter
//   K5  gather  : wave per (node,conv), LDS combine, + bf16 skip + relu
// softmax max-subtraction skipped: invariant, v bounded in (-1,~3).

constexpr int N_NODES = 50000;
constexpr int N_EDGES = 800000;
constexpr int D = 256;
constexpr float EPSV = 1.0f + 1e-06f;

typedef __attribute__((ext_vector_type(8))) short short8;
typedef __attribute__((ext_vector_type(4))) float f32x4;

__device__ __forceinline__ unsigned short f2bf(float f) {
    unsigned int b = __float_as_uint(f);
    unsigned int r = (b + 0x7FFFu + ((b >> 16) & 1u)) >> 16;   // RNE
    return (unsigned short)r;
}
__device__ __forceinline__ float bf2f(unsigned short u) {
    return __uint_as_float(((unsigned int)u) << 16);
}

// ---------------- prep: cvt_x + cvt_w + hist (independent phases) ------------
__global__ __launch_bounds__(256) void prep_kernel(
    const float4* __restrict__ x, ushort4* __restrict__ xb, int n4,
    const float* __restrict__ W0, const float* __restrict__ W1,
    const float* __restrict__ W2, unsigned short* __restrict__ wbT,
    const int* __restrict__ il, const int* __restrict__ iu,
    int* __restrict__ cl, int* __restrict__ cu,
    int* __restrict__ rkl, int* __restrict__ rku)
{
    int gid = blockIdx.x * 256 + threadIdx.x;
    int gsz = gridDim.x * 256;
    for (int i = gid; i < n4; i += gsz) {
        float4 v = x[i];
        ushort4 o;
        o.x = f2bf(v.x); o.y = f2bf(v.y); o.z = f2bf(v.z); o.w = f2bf(v.w);
        xb[i] = o;
    }
    for (int i = gid; i < 3 * 65536; i += gsz) {
        int z = i >> 16, rem = i & 65535;
        int k = rem >> 8, n = rem & 255;
        const float* W = (z == 0) ? W0 : (z == 1) ? W1 : W2;
        wbT[(size_t)z * 65536 + (size_t)n * 256 + k] = f2bf(W[(size_t)k * 256 + n]);
    }
    for (int e = gid; e < N_EDGES; e += gsz) {
        rkl[e] = atomicAdd(&cl[il[e]], 1);
        rku[e] = atomicAdd(&cu[iu[e]], 1);
    }
}

// ---------------- MFMA GEMM: BM=128, BN=64, B strip in LDS -------------------
// frag maps (verified): A: lane l elem i -> A[l%16][8*(l/16)+i]
//                       B: lane l elem i -> B[8*(l/16)+i][l%16]
//                       C: lane l reg r  -> C[4*(l/16)+r][l%16]
__global__ __launch_bounds__(256) void gemm_lds_kernel(
    const unsigned short* __restrict__ xb, const unsigned short* __restrict__ wbT,
    unsigned short* __restrict__ xml, unsigned short* __restrict__ xmu,
    unsigned short* __restrict__ skipb, int M)
{
    const int wz = blockIdx.z;
    const int tid = threadIdx.x;
    const int w = tid >> 6, lane = tid & 63;
    const int r16 = lane & 15, g = lane >> 4;
    const int m0 = blockIdx.x * 128 + w * 32;
    const int n0 = blockIdx.y * 64;

    __shared__ short8 bs[8][4][64];
    {
        const unsigned short* wb = wbT + (size_t)wz * 65536;
        #pragma unroll
        for (int c = tid; c < 2048; c += 256) {
            int kt = c >> 8, nf = (c >> 6) & 3, l = c & 63;
            bs[kt][nf][l] = *reinterpret_cast<const short8*>(
                wb + (size_t)(n0 + nf * 16 + (l & 15)) * 256 + kt * 32 + 8 * (l >> 4));
        }
    }
    __syncthreads();

    const int ar0 = min(m0 + r16, M - 1);
    const int ar1 = min(m0 + 16 + r16, M - 1);
    const unsigned short* pa0 = xb + (size_t)ar0 * 256 + 8 * g;
    const unsigned short* pa1 = xb + (size_t)ar1 * 256 + 8 * g;

    f32x4 acc[2][4];
    #pragma unroll
    for (int mf = 0; mf < 2; ++mf)
        #pragma unroll
        for (int nf = 0; nf < 4; ++nf)
            acc[mf][nf] = (f32x4){0.f, 0.f, 0.f, 0.f};

    #pragma unroll
    for (int kt = 0; kt < 8; ++kt) {
        short8 a0 = *reinterpret_cast<const short8*>(pa0 + kt * 32);
        short8 a1 = *reinterpret_cast<const short8*>(pa1 + kt * 32);
        #pragma unroll
        for (int nf = 0; nf < 4; ++nf) {
            short8 bf = bs[kt][nf][lane];
            acc[0][nf] = __builtin_amdgcn_mfma_f32_16x16x32_bf16(a0, bf, acc[0][nf], 0, 0, 0);
            acc[1][nf] = __builtin_amdgcn_mfma_f32_16x16x32_bf16(a1, bf, acc[1][nf], 0, 0, 0);
        }
    }

    unsigned short* dst = (wz == 0) ? xml : (wz == 1) ? xmu : skipb;
    const float scale = (wz == 2) ? EPSV : 1.0f;
    #pragma unroll
    for (int mf = 0; mf < 2; ++mf)
        #pragma unroll
        for (int r = 0; r < 4; ++r) {
            int row = m0 + mf * 16 + g * 4 + r;
            if (row < M) {
                #pragma unroll
                for (int nf = 0; nf < 4; ++nf)
                    dst[(size_t)row * 256 + n0 + nf * 16 + r16] = f2bf(acc[mf][nf][r] * scale);
            }
        }
}

// ---------------- single-kernel decoupled-lookback scan ----------------------
// fv[c*64+b] = block b's local total + 1 (0 = not ready). 98 blocks all
// co-resident (256 CUs) -> spin-wait is deadlock-free.
__global__ __launch_bounds__(1024) void scan_kernel(
    const int* __restrict__ cnt0, int* __restrict__ ro0,
    const int* __restrict__ cnt1, int* __restrict__ ro1,
    int* __restrict__ fv, int n)
{
    int c = blockIdx.y;
    const int* cnt = c ? cnt1 : cnt0;
    int* ro = c ? ro1 : ro0;
    int b = blockIdx.x;
    __shared__ int sm[1024];
    __shared__ int s_prefix;
    int tid = threadIdx.x;
    int i = b * 1024 + tid;
    int v = (i < n) ? cnt[i] : 0;
    sm[tid] = v;
    __syncthreads();
    #pragma unroll
    for (int off = 1; off < 1024; off <<= 1) {
        int t = (tid >= off) ? sm[tid - off] : 0;
        __syncthreads();
        sm[tid] += t;
        __syncthreads();
    }
    int total = sm[1023];
    if (tid == 0) atomicExch(&fv[c * 64 + b], total + 1);   // value rides the atomic
    if (tid < 64) {
        int p = 0;
        if (tid < b) {
            int f;
            while ((f = atomicAdd(&fv[c * 64 + tid], 0)) == 0) {}
            p = f - 1;
        }
        #pragma unroll
        for (int off = 32; off; off >>= 1) p += __shfl_xor(p, off);
        if (tid == 0) s_prefix = p;
    }
    __syncthreads();
    int prefix = s_prefix;
    if (i < n) ro[i] = prefix + sm[tid] - v;                // global exclusive
    if (tid == 0 && b == (int)gridDim.x - 1) ro[n] = prefix + total;
}

// ---------------- fused att scalars + CSR scatter -----------------------------
__global__ __launch_bounds__(256) void att_scatter_kernel(
    const unsigned short* __restrict__ xml, const unsigned short* __restrict__ xmu,
    const float* __restrict__ att_l, const float* __restrict__ att_u,
    float* __restrict__ al, float* __restrict__ bl,
    float* __restrict__ au, float* __restrict__ bu, int n_ab,
    const int* __restrict__ il, const float* __restrict__ vl,
    const int* __restrict__ rol, const int* __restrict__ rkl, int2* __restrict__ egl,
    const int* __restrict__ iu, const float* __restrict__ vu,
    const int* __restrict__ rou, const int* __restrict__ rku, int2* __restrict__ egu)
{
    int bx = (int)blockIdx.x;
    if (bx < n_ab) {
        // ---- attention scalars: one wave per node ----
        int node = (int)((bx * 256 + threadIdx.x) >> 6);
        int lane = threadIdx.x & 63;
        if (node >= N_NODES) return;
        int o = lane * 4;
        ushort4 ul = *reinterpret_cast<const ushort4*>(xml + (size_t)node * 256 + o);
        ushort4 uu = *reinterpret_cast<const ushort4*>(xmu + (size_t)node * 256 + o);
        float l0 = bf2f(ul.x), l1 = bf2f(ul.y), l2 = bf2f(ul.z), l3 = bf2f(ul.w);
        float u0 = bf2f(uu.x), u1 = bf2f(uu.y), u2 = bf2f(uu.z), u3 = bf2f(uu.w);
        float p[4];
        p[0] = l0 * att_l[o] + l1 * att_l[o + 1] + l2 * att_l[o + 2] + l3 * att_l[o + 3];
        p[1] = l0 * att_l[D + o] + l1 * att_l[D + o + 1] + l2 * att_l[D + o + 2] + l3 * att_l[D + o + 3];
        p[2] = u0 * att_u[o] + u1 * att_u[o + 1] + u2 * att_u[o + 2] + u3 * att_u[o + 3];
        p[3] = u0 * att_u[D + o] + u1 * att_u[D + o + 1] + u2 * att_u[D + o + 2] + u3 * att_u[D + o + 3];
        #pragma unroll
        for (int off = 32; off; off >>= 1)
            #pragma unroll
            for (int c = 0; c < 4; ++c)
                p[c] += __shfl_down(p[c], off);
        if (lane == 0) { al[node] = p[0]; bl[node] = p[1]; au[node] = p[2]; bu[node] = p[3]; }
    } else {
        // ---- scatter (rank-based, no atomics) ----
        int e = (bx - n_ab) * 256 + threadIdx.x;
        if (e >= N_EDGES) return;
        int2 p; p.x = il[N_EDGES + e]; p.y = __float_as_int(vl[e]);
        egl[rol[il[e]] + rkl[e]] = p;
        int2 q; q.x = iu[N_EDGES + e]; q.y = __float_as_int(vu[e]);
        egu[rou[iu[e]] + rku[e]] = q;
    }
}

// ---------------- gather: wave per (node, conv) -------------------------------
__device__ __forceinline__ float wave_sum(float v) {
    #pragma unroll
    for (int off = 32; off; off >>= 1) v += __shfl_xor(v, off);
    return v;
}

__device__ __forceinline__ void pv_accum(
    int lane, float invs, float evl, int srcl, int m,
    const unsigned short* __restrict__ xm, float4& acc)
{
    int t = 0;
    for (; t + 4 <= m; t += 4) {
        float w0 = __shfl(evl, t)     * invs;
        float w1 = __shfl(evl, t + 1) * invs;
        float w2 = __shfl(evl, t + 2) * invs;
        float w3 = __shfl(evl, t + 3) * invs;
        int s0 = __shfl(srcl, t);
        int s1 = __shfl(srcl, t + 1);
        int s2 = __shfl(srcl, t + 2);
        int s3 = __shfl(srcl, t + 3);
        ushort4 u0 = *reinterpret_cast<const ushort4*>(xm + (size_t)s0 * 256 + lane * 4);
        ushort4 u1 = *reinterpret_cast<const ushort4*>(xm + (size_t)s1 * 256 + lane * 4);
        ushort4 u2 = *reinterpret_cast<const ushort4*>(xm + (size_t)s2 * 256 + lane * 4);
        ushort4 u3 = *reinterpret_cast<const ushort4*>(xm + (size_t)s3 * 256 + lane * 4);
        acc.x += w0 * bf2f(u0.x) + w1 * bf2f(u1.x) + w2 * bf2f(u2.x) + w3 * bf2f(u3.x);
        acc.y += w0 * bf2f(u0.y) + w1 * bf2f(u1.y) + w2 * bf2f(u2.y) + w3 * bf2f(u3.y);
        acc.z += w0 * bf2f(u0.z) + w1 * bf2f(u1.z) + w2 * bf2f(u2.z) + w3 * bf2f(u3.z);
        acc.w += w0 * bf2f(u0.w) + w1 * bf2f(u1.w) + w2 * bf2f(u2.w) + w3 * bf2f(u3.w);
    }
    for (; t < m; ++t) {
        float w0 = __shfl(evl, t) * invs;
        int   s0 = __shfl(srcl, t);
        ushort4 u0 = *reinterpret_cast<const ushort4*>(xm + (size_t)s0 * 256 + lane * 4);
        acc.x += w0 * bf2f(u0.x);
        acc.y += w0 * bf2f(u0.y);
        acc.z += w0 * bf2f(u0.z);
        acc.w += w0 * bf2f(u0.w);
    }
}

__device__ __forceinline__ void conv_accum(
    int node, int lane,
    const int* __restrict__ ro, const int2* __restrict__ eg,
    const float* __restrict__ a, const float* __restrict__ b,
    const unsigned short* __restrict__ xm, float4& acc)
{
    int rs = ro[node], re = ro[node + 1];
    int deg = re - rs;
    if (deg <= 0) return;
    float ai = a[node];
    if (deg <= 64) {
        float evl = 0.f; int srcl = 0;
        if (lane < deg) {
            int2 p = eg[rs + lane];
            srcl = p.x;
            float xv = ai + b[srcl];
            float sc = (xv > 0.f) ? xv : (expf(xv) - 1.f);
            evl = expf(sc * __int_as_float(p.y));
        }
        float invs = 1.f / wave_sum(evl);
        pv_accum(lane, invs, evl, srcl, deg, xm, acc);
    } else {
        float s = 0.f;
        for (int c = rs; c < re; c += 64) {
            int m = min(64, re - c);
            float evl = 0.f;
            if (lane < m) {
                int2 p = eg[c + lane];
                float xv = ai + b[p.x];
                float sc = (xv > 0.f) ? xv : (expf(xv) - 1.f);
                evl = expf(sc * __int_as_float(p.y));
            }
            s += wave_sum(evl);
        }
        float invs = 1.f / s;
        for (int c = rs; c < re; c += 64) {
            int m = min(64, re - c);
            float evl = 0.f; int srcl = 0;
            if (lane < m) {
                int2 p = eg[c + lane];
                srcl = p.x;
                float xv = ai + b[srcl];
                float sc = (xv > 0.f) ? xv : (expf(xv) - 1.f);
                evl = expf(sc * __int_as_float(p.y));
            }
            pv_accum(lane, invs, evl, srcl, m, xm, acc);
        }
    }
}

__global__ __launch_bounds__(256) void gather_kernel(
    const int* __restrict__ rol, const int2* __restrict__ egl,
    const float* __restrict__ al, const float* __restrict__ bl,
    const unsigned short* __restrict__ xml,
    const int* __restrict__ rou, const int2* __restrict__ egu,
    const float* __restrict__ au, const float* __restrict__ bu,
    const unsigned short* __restrict__ xmu,
    const unsigned short* __restrict__ skipb, float4* __restrict__ out)
{
    int tid = threadIdx.x;
    int slot = tid >> 7;            // 0/1: which node of this block
    int conv = (tid >> 6) & 1;      // 0=lower, 1=upper
    int lane = tid & 63;
    int node = blockIdx.x * 2 + slot;
    __shared__ float4 red[2][64];
    float4 acc = make_float4(0.f, 0.f, 0.f, 0.f);
    if (node < N_NODES) {
        if (conv == 0) conv_accum(node, lane, rol, egl, al, bl, xml, acc);
        else           conv_accum(node, lane, rou, egu, au, bu, xmu, acc);
    }
    if (conv == 1) red[slot][lane] = acc;
    __syncthreads();
    if (conv == 0 && node < N_NODES) {
        float4 o = red[slot][lane];
        ushort4 sk = *reinterpret_cast<const ushort4*>(skipb + (size_t)node * 256 + lane * 4);
        acc.x = fmaxf(acc.x + o.x + bf2f(sk.x), 0.f);
        acc.y = fmaxf(acc.y + o.y + bf2f(sk.y), 0.f);
        acc.z = fmaxf(acc.z + o.z + bf2f(sk.z), 0.f);
        acc.w = fmaxf(acc.w + o.w + bf2f(sk.w), 0.f);
        out[(size_t)node * 64 + lane] = acc;
    }
}

extern "C" void kernel_launch(void* const* d_in, const int* in_sizes, int n_in,
                              void* d_out, int out_size, void* d_ws, size_t ws_size,
                              hipStream_t stream)
{
    (void)in_sizes; (void)n_in; (void)out_size; (void)ws_size;
    const float* x        = (const float*)d_in[0];
    const int*   low_idx  = (const int*)  d_in[1];
    const float* low_vals = (const float*)d_in[2];
    const int*   up_idx   = (const int*)  d_in[3];
    const float* up_vals  = (const float*)d_in[4];
    const float* W_lower  = (const float*)d_in[5];
    const float* att_low  = (const float*)d_in[6];
    const float* W_upper  = (const float*)d_in[7];
    const float* att_up   = (const float*)d_in[8];
    const float* W_lin    = (const float*)d_in[9];
    float* out = (float*)d_out;

    char* ws = (char*)d_ws;
    size_t off = 0;
    auto alloc = [&](size_t bytes) {
        void* p = ws + off;
        off += (bytes + 255) & ~(size_t)255;
        return p;
    };
    unsigned short* xb     = (unsigned short*)alloc((size_t)N_NODES * D * 2);
    unsigned short* wbT    = (unsigned short*)alloc((size_t)3 * 256 * 256 * 2);
    unsigned short* xm_low = (unsigned short*)alloc((size_t)N_NODES * D * 2);
    unsigned short* xm_up  = (unsigned short*)alloc((size_t)N_NODES * D * 2);
    unsigned short* skipb  = (unsigned short*)alloc((size_t)N_NODES * D * 2);
    float* a_low  = (float*)alloc(N_NODES * 4);
    float* b_low  = (float*)alloc(N_NODES * 4);
    float* a_up   = (float*)alloc(N_NODES * 4);
    float* b_up   = (float*)alloc(N_NODES * 4);
    // zero block: cnt_l | cnt_u | scan flags (2*64)
    int* zero_blk = (int*)alloc((2 * N_NODES + 128) * 4);
    int* cnt_low = zero_blk;
    int* cnt_up  = zero_blk + N_NODES;
    int* fv      = zero_blk + 2 * N_NODES;
    int* rk_low  = (int*)alloc((size_t)N_EDGES * 4);
    int* rk_up   = (int*)alloc((size_t)N_EDGES * 4);
    int* ro_low  = (int*)alloc((N_NODES + 1) * 4);
    int* ro_up   = (int*)alloc((N_NODES + 1) * 4);
    int2* eg_low = (int2*)alloc((size_t)N_EDGES * 8);
    int2* eg_up  = (int2*)alloc((size_t)N_EDGES * 8);

    hipMemsetAsync(zero_blk, 0, (2 * N_NODES + 128) * 4, stream);

    // 1) prep: cvt_x + cvt_w + hist/rank
    int n4 = N_NODES * D / 4;
    prep_kernel<<<2048, 256, 0, stream>>>(
        (const float4*)x, (ushort4*)xb, n4,
        W_lower, W_upper, W_lin, wbT,
        low_idx, up_idx, cnt_low, cnt_up, rk_low, rk_up);

    // 2) MFMA GEMM with LDS-staged B (skip path -> bf16 skipb)
    dim3 ggrid((N_NODES + 127) / 128, 4, 3);
    gemm_lds_kernel<<<ggrid, 256, 0, stream>>>(xb, wbT, xm_low, xm_up, skipb, N_NODES);

    // 3) decoupled-lookback scan (single dispatch)
    dim3 sgrid((N_NODES + 1023) / 1024, 2);
    scan_kernel<<<sgrid, 1024, 0, stream>>>(cnt_low, ro_low, cnt_up, ro_up, fv, N_NODES);

    // 4) fused att scalars + scatter
    int ablocks = (N_NODES + 3) / 4;
    int eblocks = (N_EDGES + 255) / 256;
    att_scatter_kernel<<<ablocks + eblocks, 256, 0, stream>>>(
        xm_low, xm_up, att_low, att_up, a_low, b_low, a_up, b_up, ablocks,
        low_idx, low_vals, ro_low, rk_low, eg_low,
        up_idx,  up_vals,  ro_up,  rk_up,  eg_up);

    // 5) gather: wave per (node, conv) + skip + relu
    int gblocks = (N_NODES + 1) / 2;
    gather_kernel<<<gblocks, 256, 0, stream>>>(
        ro_low, eg_low, a_low, b_low, xm_low,
        ro_up,  eg_up,  a_up,  b_up,  xm_up,
        skipb, (float4*)out);
}

// Round 8
// 450.117 us; speedup vs baseline: 1.0102x; 1.0102x over previous
//
#include <hip/hip_runtime.h>
#include <hip/hip_bf16.h>

// CANLayer round 8: register-A z-loop GEMM, 3-phase scan (reverted),
//                   ev precomputed in scatter.
//   K0  memset  : zero cnt_l|cnt_u
//   K1  prep    : cvt_x (bf16) + cvt_w (bf16,T) + hist/rank   [grid-stride]
//   K2  gemm    : per block (128 rows x 64 cols): A frags in regs ONCE,
//                 loop z=0..2 restaging 32KB B strip; xm/skipb bf16
//   K3  att     : a/b scalars for both convs (one dispatch)
//   K4  scan    : 3-phase parallel exclusive scan -> ro
//   K5  scatter : eg[ro[tgt]+rank[e]] = {src, ev}; ev=exp(elu(a+b)*val)
//   K6  gather  : wave per (node,conv), sum ev + PV, LDS combine,
//                 + bf16 skip + relu
// softmax max-subtraction skipped: invariant, v bounded (exp arg < ~6).

constexpr int N_NODES = 50000;
constexpr int N_EDGES = 800000;
constexpr int D = 256;
constexpr float EPSV = 1.0f + 1e-06f;

typedef __attribute__((ext_vector_type(8))) short short8;
typedef __attribute__((ext_vector_type(4))) float f32x4;

__device__ __forceinline__ unsigned short f2bf(float f) {
    unsigned int b = __float_as_uint(f);
    unsigned int r = (b + 0x7FFFu + ((b >> 16) & 1u)) >> 16;   // RNE
    return (unsigned short)r;
}
__device__ __forceinline__ float bf2f(unsigned short u) {
    return __uint_as_float(((unsigned int)u) << 16);
}

// ---------------- prep: cvt_x + cvt_w + hist (independent phases) ------------
__global__ __launch_bounds__(256) void prep_kernel(
    const float4* __restrict__ x, ushort4* __restrict__ xb, int n4,
    const float* __restrict__ W0, const float* __restrict__ W1,
    const float* __restrict__ W2, unsigned short* __restrict__ wbT,
    const int* __restrict__ il, const int* __restrict__ iu,
    int* __restrict__ cl, int* __restrict__ cu,
    int* __restrict__ rkl, int* __restrict__ rku)
{
    int gid = blockIdx.x * 256 + threadIdx.x;
    int gsz = gridDim.x * 256;
    for (int i = gid; i < n4; i += gsz) {
        float4 v = x[i];
        ushort4 o;
        o.x = f2bf(v.x); o.y = f2bf(v.y); o.z = f2bf(v.z); o.w = f2bf(v.w);
        xb[i] = o;
    }
    for (int i = gid; i < 3 * 65536; i += gsz) {
        int z = i >> 16, rem = i & 65535;
        int k = rem >> 8, n = rem & 255;
        const float* W = (z == 0) ? W0 : (z == 1) ? W1 : W2;
        wbT[(size_t)z * 65536 + (size_t)n * 256 + k] = f2bf(W[(size_t)k * 256 + n]);
    }
    for (int e = gid; e < N_EDGES; e += gsz) {
        rkl[e] = atomicAdd(&cl[il[e]], 1);
        rku[e] = atomicAdd(&cu[iu[e]], 1);
    }
}

// ---------------- MFMA GEMM: BM=128, BN=64, A frags in regs, z-loop ----------
// frag maps (verified): A: lane l elem i -> A[l%16][8*(l/16)+i]
//                       B: lane l elem i -> B[8*(l/16)+i][l%16]
//                       C: lane l reg r  -> C[4*(l/16)+r][l%16]
__global__ __launch_bounds__(256) void gemm_zreg_kernel(
    const unsigned short* __restrict__ xb, const unsigned short* __restrict__ wbT,
    unsigned short* __restrict__ xml, unsigned short* __restrict__ xmu,
    unsigned short* __restrict__ skipb, int M)
{
    const int tid = threadIdx.x;
    const int w = tid >> 6, lane = tid & 63;
    const int r16 = lane & 15, g = lane >> 4;
    const int m0 = blockIdx.x * 128 + w * 32;
    const int n0 = blockIdx.y * 64;

    __shared__ short8 bs[8][4][64];

    // ---- load all A fragments for this wave's 32 rows (once) ----
    const int ar0 = min(m0 + r16, M - 1);
    const int ar1 = min(m0 + 16 + r16, M - 1);
    const unsigned short* pa0 = xb + (size_t)ar0 * 256 + 8 * g;
    const unsigned short* pa1 = xb + (size_t)ar1 * 256 + 8 * g;
    short8 af[2][8];
    #pragma unroll
    for (int kt = 0; kt < 8; ++kt) {
        af[0][kt] = *reinterpret_cast<const short8*>(pa0 + kt * 32);
        af[1][kt] = *reinterpret_cast<const short8*>(pa1 + kt * 32);
    }

    for (int z = 0; z < 3; ++z) {
        __syncthreads();   // previous z's bs reads done
        {
            const unsigned short* wb = wbT + (size_t)z * 65536;
            #pragma unroll
            for (int c = tid; c < 2048; c += 256) {
                int kt = c >> 8, nf = (c >> 6) & 3, l = c & 63;
                bs[kt][nf][l] = *reinterpret_cast<const short8*>(
                    wb + (size_t)(n0 + nf * 16 + (l & 15)) * 256 + kt * 32 + 8 * (l >> 4));
            }
        }
        __syncthreads();

        f32x4 acc[2][4];
        #pragma unroll
        for (int mf = 0; mf < 2; ++mf)
            #pragma unroll
            for (int nf = 0; nf < 4; ++nf)
                acc[mf][nf] = (f32x4){0.f, 0.f, 0.f, 0.f};

        #pragma unroll
        for (int kt = 0; kt < 8; ++kt) {
            #pragma unroll
            for (int nf = 0; nf < 4; ++nf) {
                short8 bf = bs[kt][nf][lane];
                acc[0][nf] = __builtin_amdgcn_mfma_f32_16x16x32_bf16(af[0][kt], bf, acc[0][nf], 0, 0, 0);
                acc[1][nf] = __builtin_amdgcn_mfma_f32_16x16x32_bf16(af[1][kt], bf, acc[1][nf], 0, 0, 0);
            }
        }

        unsigned short* dst = (z == 0) ? xml : (z == 1) ? xmu : skipb;
        const float scale = (z == 2) ? EPSV : 1.0f;
        #pragma unroll
        for (int mf = 0; mf < 2; ++mf)
            #pragma unroll
            for (int r = 0; r < 4; ++r) {
                int row = m0 + mf * 16 + g * 4 + r;
                if (row < M) {
                    #pragma unroll
                    for (int nf = 0; nf < 4; ++nf)
                        dst[(size_t)row * 256 + n0 + nf * 16 + r16] = f2bf(acc[mf][nf][r] * scale);
                }
            }
    }
}

// ---------------- att scalars for both convs (one wave per node) -------------
__global__ __launch_bounds__(256) void att_both_kernel(
    const unsigned short* __restrict__ xml, const unsigned short* __restrict__ xmu,
    const float* __restrict__ att_l, const float* __restrict__ att_u,
    float* __restrict__ al, float* __restrict__ bl,
    float* __restrict__ au, float* __restrict__ bu, int n)
{
    int node = (int)((blockIdx.x * 256 + threadIdx.x) >> 6);
    int lane = threadIdx.x & 63;
    if (node >= n) return;
    int o = lane * 4;
    ushort4 ul = *reinterpret_cast<const ushort4*>(xml + (size_t)node * 256 + o);
    ushort4 uu = *reinterpret_cast<const ushort4*>(xmu + (size_t)node * 256 + o);
    float l0 = bf2f(ul.x), l1 = bf2f(ul.y), l2 = bf2f(ul.z), l3 = bf2f(ul.w);
    float u0 = bf2f(uu.x), u1 = bf2f(uu.y), u2 = bf2f(uu.z), u3 = bf2f(uu.w);
    float p[4];
    p[0] = l0 * att_l[o] + l1 * att_l[o + 1] + l2 * att_l[o + 2] + l3 * att_l[o + 3];
    p[1] = l0 * att_l[D + o] + l1 * att_l[D + o + 1] + l2 * att_l[D + o + 2] + l3 * att_l[D + o + 3];
    p[2] = u0 * att_u[o] + u1 * att_u[o + 1] + u2 * att_u[o + 2] + u3 * att_u[o + 3];
    p[3] = u0 * att_u[D + o] + u1 * att_u[D + o + 1] + u2 * att_u[D + o + 2] + u3 * att_u[D + o + 3];
    #pragma unroll
    for (int off = 32; off; off >>= 1)
        #pragma unroll
        for (int c = 0; c < 4; ++c)
            p[c] += __shfl_down(p[c], off);
    if (lane == 0) { al[node] = p[0]; bl[node] = p[1]; au[node] = p[2]; bu[node] = p[3]; }
}

// ---------------- 3-phase scan (round-6 proven) -------------------------------
__global__ __launch_bounds__(1024) void scan_local_kernel(
    const int* __restrict__ cnt0, int* __restrict__ ro0,
    const int* __restrict__ cnt1, int* __restrict__ ro1,
    int* __restrict__ bsum, int n)
{
    int c = blockIdx.y;
    const int* cnt = c ? cnt1 : cnt0;
    int* ro = c ? ro1 : ro0;
    __shared__ int sm[1024];
    int tid = threadIdx.x;
    int i = blockIdx.x * 1024 + tid;
    int v = (i < n) ? cnt[i] : 0;
    sm[tid] = v;
    __syncthreads();
    #pragma unroll
    for (int off = 1; off < 1024; off <<= 1) {
        int t = (tid >= off) ? sm[tid - off] : 0;
        __syncthreads();
        sm[tid] += t;
        __syncthreads();
    }
    if (i < n) ro[i] = sm[tid] - v;                 // local exclusive
    if (tid == 1023) bsum[c * 64 + blockIdx.x] = sm[1023];
}

__global__ __launch_bounds__(128) void scan_bsum_kernel(int* __restrict__ bsum, int nb)
{
    int c = threadIdx.x >> 6, lane = threadIdx.x & 63;
    int v = (lane < nb) ? bsum[c * 64 + lane] : 0;
    int orig = v;
    #pragma unroll
    for (int off = 1; off < 64; off <<= 1) {
        int t = __shfl_up(v, off);
        if (lane >= off) v += t;
    }
    if (lane < nb) bsum[c * 64 + lane] = v - orig;  // exclusive block offsets
}

__global__ __launch_bounds__(256) void scan_apply_kernel(
    int* __restrict__ ro0, int* __restrict__ ro1,
    const int* __restrict__ bsum, int n)
{
    int c = blockIdx.y;
    int* ro = c ? ro1 : ro0;
    int i = blockIdx.x * 256 + threadIdx.x;
    if (i < n) ro[i] += bsum[c * 64 + (i >> 10)];
    if (i == 0) ro[n] = N_EDGES;
}

// ---------------- scatter + edge score: eg = {src, ev} ------------------------
__global__ __launch_bounds__(256) void scatter_ev_kernel(
    const int* __restrict__ il, const float* __restrict__ vl,
    const int* __restrict__ rol, const int* __restrict__ rkl,
    const float* __restrict__ al, const float* __restrict__ blv,
    int2* __restrict__ egl,
    const int* __restrict__ iu, const float* __restrict__ vu,
    const int* __restrict__ rou, const int* __restrict__ rku,
    const float* __restrict__ au, const float* __restrict__ buv,
    int2* __restrict__ egu)
{
    int e = blockIdx.x * 256 + threadIdx.x;
    if (e >= N_EDGES) return;
    {
        int t = il[e], s = il[N_EDGES + e];
        float xv = al[t] + blv[s];
        float sc = (xv > 0.f) ? xv : (expf(xv) - 1.f);
        float ev = expf(sc * vl[e]);
        int2 p; p.x = s; p.y = __float_as_int(ev);
        egl[rol[t] + rkl[e]] = p;
    }
    {
        int t = iu[e], s = iu[N_EDGES + e];
        float xv = au[t] + buv[s];
        float sc = (xv > 0.f) ? xv : (expf(xv) - 1.f);
        float ev = expf(sc * vu[e]);
        int2 q; q.x = s; q.y = __float_as_int(ev);
        egu[rou[t] + rku[e]] = q;
    }
}

// ---------------- gather: wave per (node, conv) -------------------------------
__device__ __forceinline__ float wave_sum(float v) {
    #pragma unroll
    for (int off = 32; off; off >>= 1) v += __shfl_xor(v, off);
    return v;
}

__device__ __forceinline__ void pv_accum(
    int lane, float invs, float evl, int srcl, int m,
    const unsigned short* __restrict__ xm, float4& acc)
{
    int t = 0;
    for (; t + 4 <= m; t += 4) {
        float w0 = __shfl(evl, t)     * invs;
        float w1 = __shfl(evl, t + 1) * invs;
        float w2 = __shfl(evl, t + 2) * invs;
        float w3 = __shfl(evl, t + 3) * invs;
        int s0 = __shfl(srcl, t);
        int s1 = __shfl(srcl, t + 1);
        int s2 = __shfl(srcl, t + 2);
        int s3 = __shfl(srcl, t + 3);
        ushort4 u0 = *reinterpret_cast<const ushort4*>(xm + (size_t)s0 * 256 + lane * 4);
        ushort4 u1 = *reinterpret_cast<const ushort4*>(xm + (size_t)s1 * 256 + lane * 4);
        ushort4 u2 = *reinterpret_cast<const ushort4*>(xm + (size_t)s2 * 256 + lane * 4);
        ushort4 u3 = *reinterpret_cast<const ushort4*>(xm + (size_t)s3 * 256 + lane * 4);
        acc.x += w0 * bf2f(u0.x) + w1 * bf2f(u1.x) + w2 * bf2f(u2.x) + w3 * bf2f(u3.x);
        acc.y += w0 * bf2f(u0.y) + w1 * bf2f(u1.y) + w2 * bf2f(u2.y) + w3 * bf2f(u3.y);
        acc.z += w0 * bf2f(u0.z) + w1 * bf2f(u1.z) + w2 * bf2f(u2.z) + w3 * bf2f(u3.z);
        acc.w += w0 * bf2f(u0.w) + w1 * bf2f(u1.w) + w2 * bf2f(u2.w) + w3 * bf2f(u3.w);
    }
    for (; t < m; ++t) {
        float w0 = __shfl(evl, t) * invs;
        int   s0 = __shfl(srcl, t);
        ushort4 u0 = *reinterpret_cast<const ushort4*>(xm + (size_t)s0 * 256 + lane * 4);
        acc.x += w0 * bf2f(u0.x);
        acc.y += w0 * bf2f(u0.y);
        acc.z += w0 * bf2f(u0.z);
        acc.w += w0 * bf2f(u0.w);
    }
}

__device__ __forceinline__ void conv_accum(
    int node, int lane,
    const int* __restrict__ ro, const int2* __restrict__ eg,
    const unsigned short* __restrict__ xm, float4& acc)
{
    int rs = ro[node], re = ro[node + 1];
    int deg = re - rs;
    if (deg <= 0) return;
    if (deg <= 64) {
        float evl = 0.f; int srcl = 0;
        if (lane < deg) {
            int2 p = eg[rs + lane];
            srcl = p.x;
            evl = __int_as_float(p.y);
        }
        float invs = 1.f / wave_sum(evl);
        pv_accum(lane, invs, evl, srcl, deg, xm, acc);
    } else {
        float s = 0.f;
        for (int c = rs; c < re; c += 64) {
            int m = min(64, re - c);
            float evl = (lane < m) ? __int_as_float(eg[c + lane].y) : 0.f;
            s += wave_sum(evl);
        }
        float invs = 1.f / s;
        for (int c = rs; c < re; c += 64) {
            int m = min(64, re - c);
            float evl = 0.f; int srcl = 0;
            if (lane < m) {
                int2 p = eg[c + lane];
                srcl = p.x;
                evl = __int_as_float(p.y);
            }
            pv_accum(lane, invs, evl, srcl, m, xm, acc);
        }
    }
}

__global__ __launch_bounds__(256) void gather_kernel(
    const int* __restrict__ rol, const int2* __restrict__ egl,
    const unsigned short* __restrict__ xml,
    const int* __restrict__ rou, const int2* __restrict__ egu,
    const unsigned short* __restrict__ xmu,
    const unsigned short* __restrict__ skipb, float4* __restrict__ out)
{
    int tid = threadIdx.x;
    int slot = tid >> 7;            // 0/1: which node of this block
    int conv = (tid >> 6) & 1;      // 0=lower, 1=upper
    int lane = tid & 63;
    int node = blockIdx.x * 2 + slot;
    __shared__ float4 red[2][64];
    float4 acc = make_float4(0.f, 0.f, 0.f, 0.f);
    if (node < N_NODES) {
        if (conv == 0) conv_accum(node, lane, rol, egl, xml, acc);
        else           conv_accum(node, lane, rou, egu, xmu, acc);
    }
    if (conv == 1) red[slot][lane] = acc;
    __syncthreads();
    if (conv == 0 && node < N_NODES) {
        float4 o = red[slot][lane];
        ushort4 sk = *reinterpret_cast<const ushort4*>(skipb + (size_t)node * 256 + lane * 4);
        acc.x = fmaxf(acc.x + o.x + bf2f(sk.x), 0.f);
        acc.y = fmaxf(acc.y + o.y + bf2f(sk.y), 0.f);
        acc.z = fmaxf(acc.z + o.z + bf2f(sk.z), 0.f);
        acc.w = fmaxf(acc.w + o.w + bf2f(sk.w), 0.f);
        out[(size_t)node * 64 + lane] = acc;
    }
}

extern "C" void kernel_launch(void* const* d_in, const int* in_sizes, int n_in,
                              void* d_out, int out_size, void* d_ws, size_t ws_size,
                              hipStream_t stream)
{
    (void)in_sizes; (void)n_in; (void)out_size; (void)ws_size;
    const float* x        = (const float*)d_in[0];
    const int*   low_idx  = (const int*)  d_in[1];
    const float* low_vals = (const float*)d_in[2];
    const int*   up_idx   = (const int*)  d_in[3];
    const float* up_vals  = (const float*)d_in[4];
    const float* W_lower  = (const float*)d_in[5];
    const float* att_low  = (const float*)d_in[6];
    const float* W_upper  = (const float*)d_in[7];
    const float* att_up   = (const float*)d_in[8];
    const float* W_lin    = (const float*)d_in[9];
    float* out = (float*)d_out;

    char* ws = (char*)d_ws;
    size_t off = 0;
    auto alloc = [&](size_t bytes) {
        void* p = ws + off;
        off += (bytes + 255) & ~(size_t)255;
        return p;
    };
    unsigned short* xb     = (unsigned short*)alloc((size_t)N_NODES * D * 2);
    unsigned short* wbT    = (unsigned short*)alloc((size_t)3 * 256 * 256 * 2);
    unsigned short* xm_low = (unsigned short*)alloc((size_t)N_NODES * D * 2);
    unsigned short* xm_up  = (unsigned short*)alloc((size_t)N_NODES * D * 2);
    unsigned short* skipb  = (unsigned short*)alloc((size_t)N_NODES * D * 2);
    float* a_low  = (float*)alloc(N_NODES * 4);
    float* b_low  = (float*)alloc(N_NODES * 4);
    float* a_up   = (float*)alloc(N_NODES * 4);
    float* b_up   = (float*)alloc(N_NODES * 4);
    int* zero_blk = (int*)alloc(2 * N_NODES * 4);   // cnt_l | cnt_u
    int* cnt_low = zero_blk;
    int* cnt_up  = zero_blk + N_NODES;
    int* rk_low  = (int*)alloc((size_t)N_EDGES * 4);
    int* rk_up   = (int*)alloc((size_t)N_EDGES * 4);
    int* ro_low  = (int*)alloc((N_NODES + 1) * 4);
    int* ro_up   = (int*)alloc((N_NODES + 1) * 4);
    int* bsum    = (int*)alloc(2 * 64 * 4);
    int2* eg_low = (int2*)alloc((size_t)N_EDGES * 8);
    int2* eg_up  = (int2*)alloc((size_t)N_EDGES * 8);

    hipMemsetAsync(zero_blk, 0, 2 * N_NODES * 4, stream);

    // 1) prep: cvt_x + cvt_w + hist/rank
    int n4 = N_NODES * D / 4;
    prep_kernel<<<2048, 256, 0, stream>>>(
        (const float4*)x, (ushort4*)xb, n4,
        W_lower, W_upper, W_lin, wbT,
        low_idx, up_idx, cnt_low, cnt_up, rk_low, rk_up);

    // 2) MFMA GEMM: register-A, z-loop (A re-read 4x instead of 12x)
    dim3 ggrid((N_NODES + 127) / 128, 4);
    gemm_zreg_kernel<<<ggrid, 256, 0, stream>>>(xb, wbT, xm_low, xm_up, skipb, N_NODES);

    // 3) att scalars (both convs)
    int ablocks = (N_NODES + 3) / 4;
    att_both_kernel<<<ablocks, 256, 0, stream>>>(
        xm_low, xm_up, att_low, att_up, a_low, b_low, a_up, b_up, N_NODES);

    // 4) CSR scan (3-phase, proven)
    dim3 sgrid((N_NODES + 1023) / 1024, 2);
    scan_local_kernel<<<sgrid, 1024, 0, stream>>>(cnt_low, ro_low, cnt_up, ro_up,
                                                  bsum, N_NODES);
    scan_bsum_kernel<<<1, 128, 0, stream>>>(bsum, (N_NODES + 1023) / 1024);
    dim3 agrid((N_NODES + 255) / 256, 2);
    scan_apply_kernel<<<agrid, 256, 0, stream>>>(ro_low, ro_up, bsum, N_NODES);

    // 5) scatter + edge scores
    int eblocks = (N_EDGES + 255) / 256;
    scatter_ev_kernel<<<eblocks, 256, 0, stream>>>(
        low_idx, low_vals, ro_low, rk_low, a_low, b_low, eg_low,
        up_idx,  up_vals,  ro_up,  rk_up,  a_up,  b_up,  eg_up);

    // 6) gather: wave per (node, conv) + skip + relu
    int gblocks = (N_NODES + 1) / 2;
    gather_kernel<<<gblocks, 256, 0, stream>>>(
        ro_low, eg_low, xm_low,
        ro_up,  eg_up,  xm_up,
        skipb, (float4*)out);
}